// Round 2
// baseline (235.137 us; speedup 1.0000x reference)
//
#include <hip/hip_runtime.h>

// MeanEmbedding: out[b,d] = (1/len[b]) * sum_{s<len[b]} xs[b,s,d]
// xs: [B=16, S=4096, D=512] fp32, xs_len: [B] int32, out: [B, D] fp32.
//
// Single fused kernel (split-K semaphore pattern):
//  - grid (B, S/64); each 512-thread block sums a 64-row slab (4 sub-slabs
//    of 16 rows, tid>>7 selects sub-slab; 128 float4 lanes across D) and
//    LDS-reduces to ONE 2 KB partial per block (1 MB total partial traffic).
//  - release: __syncthreads; tid0 {__threadfence (L2 writeback) ->
//    atomicAdd(cnt[b])}. Last-arriving block for b acquires (__threadfence,
//    L2 inv) and reduces the <=64 partials, scales by 1/len, writes out.
//    Finalize overlaps other sequences' streaming instead of a 2nd launch.
//  - counters live in d_ws past the partials; zeroed by a 64 B memset node.
// No spin-waits (graph-capture safe), no output memset needed.

#define T      512
#define D4     128        // D/4 float4 columns
#define SLAB   64         // rows per block
#define SUB    16         // rows per sub-slab (T/D4 = 4 sub-slabs)
#define NCHMAX 64         // S/SLAB

__device__ __forceinline__ float4 f4add(float4 a, float4 b) {
    return make_float4(a.x + b.x, a.y + b.y, a.z + b.z, a.w + b.w);
}

__global__ __launch_bounds__(T) void mean_embed_fused(
    const float4* __restrict__ xs,
    const int*    __restrict__ xs_len,
    float4*       __restrict__ part,     // [B][NCHMAX][D4]
    int*          __restrict__ cnt,      // [B]
    float4*       __restrict__ out,      // [B][D4]
    int S)
{
    const int b     = blockIdx.x;
    const int chunk = blockIdx.y;
    const int L     = xs_len[b];
    const int row0  = chunk * SLAB;
    if (row0 >= L) return;                       // slab entirely masked
    const int nch = (L + SLAB - 1) / SLAB;

    const int tid = threadIdx.x;
    const int col = tid & (D4 - 1);              // float4 column 0..127
    const int sub = tid >> 7;                    // sub-slab 0..3

    const float4* base = xs + (size_t)b * S * D4;

    // ---- phase 1: stream the 16-row sub-slab ----
    float4 acc = make_float4(0.f, 0.f, 0.f, 0.f);
    const int r0 = row0 + sub * SUB;
    if (row0 + SLAB <= L) {                      // full slab fast path
        #pragma unroll
        for (int i = 0; i < SUB; ++i)
            acc = f4add(acc, base[(size_t)(r0 + i) * D4 + col]);
    } else {
        const int r1 = min(r0 + SUB, L);
        for (int s = r0; s < r1; ++s)
            acc = f4add(acc, base[(size_t)s * D4 + col]);
    }

    // ---- block LDS tree: 4 sub-slabs -> 1 partial ----
    __shared__ float4 red[T];
    red[tid] = acc;
    __syncthreads();
    if (tid < D4) {
        float4 p = f4add(f4add(red[tid],        red[tid + 128]),
                         f4add(red[tid + 256],  red[tid + 384]));
        part[((size_t)b * NCHMAX + chunk) * D4 + tid] = p;
    }
    __syncthreads();

    // ---- release + arrive ----
    __shared__ int is_last;
    if (tid == 0) {
        __threadfence();                          // release: L2 writeback
        int old = atomicAdd(&cnt[b], 1);          // device-scope
        is_last = (old == nch - 1);
    }
    __syncthreads();
    if (!is_last) return;

    // ---- last block for b: acquire + finalize ----
    __threadfence();                              // acquire: L2 invalidate

    const int cl = tid >> 7;                      // chunk lane 0..3
    float4 acc2 = make_float4(0.f, 0.f, 0.f, 0.f);
    for (int c = cl; c < nch; c += 4)
        acc2 = f4add(acc2, part[((size_t)b * NCHMAX + c) * D4 + col]);

    red[tid] = acc2;
    __syncthreads();
    if (tid < D4) {
        float4 s4 = f4add(f4add(red[tid],       red[tid + 128]),
                          f4add(red[tid + 256], red[tid + 384]));
        const float inv = 1.0f / (float)L;
        out[(size_t)b * D4 + tid] =
            make_float4(s4.x * inv, s4.y * inv, s4.z * inv, s4.w * inv);
    }
}

extern "C" void kernel_launch(void* const* d_in, const int* in_sizes, int n_in,
                              void* d_out, int out_size, void* d_ws, size_t ws_size,
                              hipStream_t stream) {
    const float4* xs     = (const float4*)d_in[0];
    const int*    xs_len = (const int*)d_in[1];
    float4*       out    = (float4*)d_out;

    const int B = in_sizes[1];                 // 16
    const int total = in_sizes[0];             // B*S*D
    const int D = 512;
    const int S = total / (B * D);             // 4096

    // ws layout: partials [B][NCHMAX][D4] float4 = 2 MB, then cnt[B] int.
    float4* part = (float4*)d_ws;
    int*    cnt  = (int*)((char*)d_ws + (size_t)B * NCHMAX * D4 * sizeof(float4));

    // counters are poisoned each call -> zero them (capture-safe, 64 B)
    hipMemsetAsync(cnt, 0, B * sizeof(int), stream);

    dim3 grid(B, S / SLAB);
    mean_embed_fused<<<grid, T, 0, stream>>>(xs, xs_len, part, cnt, out, S);
}

// Round 3
// 182.814 us; speedup vs baseline: 1.2862x; 1.2862x over previous
//
#include <hip/hip_runtime.h>

// MeanEmbedding: out[b,d] = (1/len[b]) * sum_{s<len[b]} xs[b,s,d]
// xs: [B=16, S=4096, D=512] fp32, xs_len: [B] int32, out: [B, D] fp32.
//
// Two-stage, atomic-free, fence-free reduction (R2's fused semaphore version
// regressed 4x on kernel time: 1024 in-kernel device-scope fences serialize
// at the TCC; kernel-boundary release/acquire is cheaper).
//
//  Stage 1: grid (B, S/32), 128 threads. Each block sums a 32-row slab
//           across D (128 lanes x float4, 32 independent unrolled loads in
//           flight) -> one 2 KB partial in d_ws. Blocks past len[b] exit.
//  Stage 2: grid (B, 8), 256 threads = 16 cols x 16 chunk-lanes. Each
//           thread reads <=8 valid partials, LDS tree over lanes, scale by
//           1/len, write out. 512 waves -> not latency-bound.
// No atomics, no output memset (stage 2 writes every element).

#define ROWS   32         // rows per stage-1 slab
#define T1     128        // D/4 = 512/4 float4 lanes per row
#define T2     256
#define NCH    128        // S/ROWS partial slots per sequence

__device__ __forceinline__ float4 f4add(float4 a, float4 b) {
    return make_float4(a.x + b.x, a.y + b.y, a.z + b.z, a.w + b.w);
}

__global__ __launch_bounds__(T1) void mean_embed_stage1(
    const float4* __restrict__ xs,
    const int*    __restrict__ xs_len,
    float4*       __restrict__ ws,
    int S)
{
    const int b     = blockIdx.x;
    const int chunk = blockIdx.y;
    const int L     = xs_len[b];
    const int row0  = chunk * ROWS;
    if (row0 >= L) return;                    // slab entirely masked out
    const int tid  = threadIdx.x;             // float4 column 0..127

    const float4* base = xs + (size_t)b * S * T1;

    float4 acc = make_float4(0.f, 0.f, 0.f, 0.f);
    if (row0 + ROWS <= L) {
        // full slab: 32 independent loads, fully unrolled
        #pragma unroll
        for (int i = 0; i < ROWS; ++i)
            acc = f4add(acc, base[(size_t)(row0 + i) * T1 + tid]);
    } else {
        const int row1 = min(row0 + ROWS, L);
        for (int s = row0; s < row1; ++s)
            acc = f4add(acc, base[(size_t)s * T1 + tid]);
    }

    ws[((size_t)b * NCH + chunk) * T1 + tid] = acc;
}

__global__ __launch_bounds__(T2) void mean_embed_stage2(
    const float4* __restrict__ ws,
    const int*    __restrict__ xs_len,
    float4*       __restrict__ out)
{
    const int b    = blockIdx.x;
    const int tid  = threadIdx.x;
    const int colL = tid & 15;                    // local col 0..15
    const int col  = blockIdx.y * 16 + colL;      // float4 column 0..127
    const int lane = tid >> 4;                    // chunk lane 0..15
    const int L    = xs_len[b];
    const int nch  = (L + ROWS - 1) / ROWS;       // valid partial count <=128

    float4 acc = make_float4(0.f, 0.f, 0.f, 0.f);
    for (int c = lane; c < nch; c += 16)
        acc = f4add(acc, ws[((size_t)b * NCH + c) * T1 + col]);

    __shared__ float4 red[T2];
    red[tid] = acc;
    __syncthreads();
    if (tid < 128) red[tid] = f4add(red[tid], red[tid + 128]);
    __syncthreads();
    if (tid < 64)  red[tid] = f4add(red[tid], red[tid + 64]);
    __syncthreads();
    if (tid < 32)  red[tid] = f4add(red[tid], red[tid + 32]);
    __syncthreads();
    if (tid < 16) {
        float4 s4 = f4add(red[tid], red[tid + 16]);
        const float inv = 1.0f / (float)L;
        out[(size_t)b * T1 + blockIdx.y * 16 + tid] =
            make_float4(s4.x * inv, s4.y * inv, s4.z * inv, s4.w * inv);
    }
}

extern "C" void kernel_launch(void* const* d_in, const int* in_sizes, int n_in,
                              void* d_out, int out_size, void* d_ws, size_t ws_size,
                              hipStream_t stream) {
    const float4* xs     = (const float4*)d_in[0];
    const int*    xs_len = (const int*)d_in[1];
    float4*       out    = (float4*)d_out;
    float4*       ws     = (float4*)d_ws;

    const int B = in_sizes[1];                 // 16
    const int total = in_sizes[0];             // B*S*D
    const int D = 512;
    const int S = total / (B * D);             // 4096

    // ws usage: B * NCH * 128 float4 = 4 MB (<< ws_size)
    dim3 g1(B, S / ROWS);
    mean_embed_stage1<<<g1, T1, 0, stream>>>(xs, xs_len, ws, S);

    dim3 g2(B, 8);
    mean_embed_stage2<<<g2, T2, 0, stream>>>(ws, xs_len, out);
}